// Round 15
// baseline (670.362 us; speedup 1.0000x reference)
//
#include <hip/hip_runtime.h>
#include <math.h>

#define NGENES 50000
#define NEDGES 5000
#define NNZ_C 1600000
#define NPATH 500
#define DIM 128
#define BB 64
#define MM 200
#define BMN (BB * MM)
#define NBMW 1568          // bitmap words (50176 bits >= 50000)
#define CSRCAP 400000      // marked CSR entries ~362K expected
#define NCH 32             // chunks (hist + placement, must match ccpre8)
#define RNG 12512          // gene range per row-hist role (4*12512 = 50048)
#define GSTRIDE 50048      // row partial stride
#define NT 8               // gene tiles (one per XCD)
#define TILESZ 6250        // genes per tile -> 3.2 MB of gene_embed per tile
#define NBIN (NT * NEDGES) // 40000 (tile,edge) bins
#define BIN0 50048         // k_reduce index segments
#define EDGE0 90048
#define RED_N 95048
#define SCB_BIN 40         // scan chunk-blocks for bins (40*1024 >= 40000)
#define SCB_ROW 49         // scan chunk-blocks for rows (49*1024 >= 50000)
#define SCB (SCB_BIN + SCB_ROW)
#define PKW 17             // packed mask words per (b,m): 16 + 1 pad

// ---------------- wave helpers ----------------
__device__ inline float wred_sum(float x) {
#pragma unroll
  for (int off = 32; off > 0; off >>= 1) x += __shfl_down(x, off, 64);
  return x;
}
__device__ inline int wred_sumi(int x) {
#pragma unroll
  for (int off = 32; off > 0; off >>= 1) x += __shfl_down(x, off, 64);
  return x;
}
__device__ inline float wred_max(float x) {
#pragma unroll
  for (int off = 32; off > 0; off >>= 1) x = fmaxf(x, __shfl_down(x, off, 64));
  return x;
}
__device__ inline int wave_incl_scan(int x) {
  int lane = threadIdx.x & 63;
#pragma unroll
  for (int off = 1; off < 64; off <<= 1) {
    int y = __shfl_up(x, off, 64);
    if (lane >= off) x += y;
  }
  return x;
}

// mark genes referenced by gene_ids in a bitmap
__global__ void k_mark(const int* __restrict__ gene_ids, unsigned* __restrict__ bitmap) {
  int i = blockIdx.x * blockDim.x + threadIdx.x;
  if (i >= BMN) return;
  int g = gene_ids[i];
  atomicOr(bitmap + (g >> 5), 1u << (g & 31));
}

// pack each (b,m) pathway mask row into 512 bits (mask is exactly 0.0/1.0 by
// construction: bernoulli().astype(float32)). wave per (b,m) row, ballot-based.
__global__ void k_pack(const int* __restrict__ gene_ids,
                       const float* __restrict__ gene_pathway,
                       unsigned* __restrict__ pk) {
  int bm = blockIdx.x * 4 + (threadIdx.x >> 6);
  int lane = threadIdx.x & 63;
  if (bm >= BMN) return;
  int g = gene_ids[bm];
  const float* row = gene_pathway + (size_t)g * NPATH;
  unsigned* dst = pk + (size_t)bm * PKW;
#pragma unroll
  for (int ch = 0; ch < 8; ++ch) {
    int p = ch * 64 + lane;
    float mv = (p < NPATH) ? row[p] : 0.f;
    unsigned long long mask = __ballot(mv != 0.f);
    if (lane == 0) {
      dst[2 * ch] = (unsigned)mask;
      dst[2 * ch + 1] = (unsigned)(mask >> 32);
    }
  }
  if (lane == 0) dst[16] = 0u;
}

// MERGED build histograms, atomic-free. grid (NCH, 12), 1024 thr.
__global__ void k_build(const int* __restrict__ rows, const int* __restrict__ cols,
                        const float* __restrict__ vals, const unsigned* __restrict__ bitmap,
                        float* __restrict__ pdv, int* __restrict__ pcnt,
                        int* __restrict__ pbc, float* __restrict__ pde) {
  __shared__ char smem_raw[60000];
  int c = blockIdx.x, role = blockIdx.y, tid = threadIdx.x;
  int lo = c * (NNZ_C / NCH), hi = lo + (NNZ_C / NCH);
  if (role < 4) {
    float* hs = (float*)smem_raw;
    int rlo = role * RNG;
    for (int j = tid; j < RNG; j += 1024) hs[j] = 0.f;
    __syncthreads();
    for (int i = lo + tid; i < hi; i += 1024) {
      int r = rows[i];
      unsigned d = (unsigned)(r - rlo);
      if (d < RNG) atomicAdd(&hs[d], vals[i]);
    }
    __syncthreads();
    float* dst = pdv + (size_t)c * GSTRIDE + rlo;
    for (int j = tid; j < RNG; j += 1024) dst[j] = hs[j];
  } else if (role < 8) {
    int* hs = (int*)smem_raw;
    unsigned* bm = (unsigned*)(smem_raw + RNG * 4);
    int rlo = (role - 4) * RNG;
    for (int j = tid; j < RNG; j += 1024) hs[j] = 0;
    for (int j = tid; j < NBMW; j += 1024) bm[j] = bitmap[j];
    __syncthreads();
    for (int i = lo + tid; i < hi; i += 1024) {
      int r = rows[i];
      unsigned d = (unsigned)(r - rlo);
      if (d < RNG && ((bm[r >> 5] >> (r & 31)) & 1)) atomicAdd(&hs[d], 1);
    }
    __syncthreads();
    int* dst = pcnt + (size_t)c * GSTRIDE + rlo;
    for (int j = tid; j < RNG; j += 1024) dst[j] = hs[j];
  } else {
    int p = role - 8;
    int* hc = (int*)smem_raw;                    // 40000 B
    float* hs = (float*)(smem_raw + 40000);      // 20000 B
    for (int j = tid; j < 2 * NEDGES; j += 1024) hc[j] = 0;
    for (int j = tid; j < NEDGES; j += 1024) hs[j] = 0.f;
    __syncthreads();
    for (int i = lo + tid; i < hi; i += 1024) {
      int r = rows[i];
      int t = r / TILESZ;
      if ((t >> 1) != p) continue;
      int e = cols[i];
      atomicAdd(&hc[(t & 1) * NEDGES + e], 1);
      atomicAdd(&hs[e], vals[i]);
    }
    __syncthreads();
    for (int j = tid; j < 2 * NEDGES; j += 1024) {
      int h = j / NEDGES, e = j - h * NEDGES;
      pbc[(size_t)c * NBIN + (2 * p + h) * NEDGES + e] = hc[j];
    }
    for (int j = tid; j < NEDGES; j += 1024)
      pde[((size_t)c * 4 + p) * NEDGES + j] = hs[j];
  }
}

// merged reduce: genes -> dv_inv,row_cnt; bins -> ccpre8 + edge-major cnt8em; edges -> de_inv
__global__ void k_reduce(const float* __restrict__ pdv, const int* __restrict__ pcnt,
                         const int* __restrict__ pbc, const float* __restrict__ pde,
                         float* __restrict__ dv_inv, int* __restrict__ row_cnt,
                         int* __restrict__ ccpre8, int* __restrict__ cnt8em,
                         float* __restrict__ de_inv) {
  int idx = blockIdx.x * 256 + threadIdx.x;
  if (idx < NGENES) {
    float s = 0.f;
    int n = 0;
    for (int c = 0; c < NCH; ++c) {
      s += pdv[(size_t)c * GSTRIDE + idx];
      n += pcnt[(size_t)c * GSTRIDE + idx];
    }
    dv_inv[idx] = 1.f / sqrtf(s + 1e-6f);
    row_cnt[idx] = n;
  } else if (idx >= BIN0 && idx < BIN0 + NBIN) {
    int b = idx - BIN0;  // tile-major bin id
    int t = b / NEDGES, e = b - t * NEDGES;
    int run = 0;
    for (int c = 0; c < NCH; ++c) {
      ccpre8[(size_t)c * NBIN + b] = run;
      run += pbc[(size_t)c * NBIN + b];
    }
    cnt8em[(e << 3) | t] = run;  // edge-major total (scan order)
  } else if (idx >= EDGE0 && idx < EDGE0 + NEDGES) {
    int e = idx - EDGE0;
    float s = 0.f;
    for (int cp = 0; cp < NCH * 4; ++cp) s += pde[(size_t)cp * NEDGES + e];
    de_inv[e] = 1.f / (s + 1e-6f);
  }
}

// ---- hierarchical coalesced scans over cnt8em (40000) and row_cnt (50000) ----
__global__ void k_sc1(const int* __restrict__ cnt8em, const int* __restrict__ row_cnt,
                      int* __restrict__ bsum) {
  __shared__ int wsum[4];
  int blk = blockIdx.x, t = threadIdx.x, lane = t & 63, wid = t >> 6;
  const int* in;
  int base, n;
  if (blk < SCB_BIN) { in = cnt8em; base = blk * 1024; n = NBIN; }
  else { in = row_cnt; base = (blk - SCB_BIN) * 1024; n = NGENES; }
  int s = 0;
#pragma unroll
  for (int k = 0; k < 4; ++k) {
    int e = base + t + k * 256;
    if (e < n) s += in[e];
  }
  s = wred_sumi(s);
  if (lane == 0) wsum[wid] = s;
  __syncthreads();
  if (t == 0) bsum[blk] = wsum[0] + wsum[1] + wsum[2] + wsum[3];
}

__global__ void k_sc2(const int* __restrict__ bsum, int* __restrict__ boff) {
  int t = threadIdx.x, lane = t & 63, wid = t >> 6;
  if (wid == 0) {
    int x = (lane < SCB_BIN) ? bsum[lane] : 0;
    int incl = wave_incl_scan(x);
    if (lane < SCB_BIN) boff[lane] = incl - x;
  } else {
    int x = (lane < SCB_ROW) ? bsum[SCB_BIN + lane] : 0;
    int incl = wave_incl_scan(x);
    if (lane < SCB_ROW) boff[SCB_BIN + lane] = incl - x;
  }
}

__global__ void k_sc3(const int* __restrict__ cnt8em, const int* __restrict__ row_cnt,
                      const int* __restrict__ boff,
                      int* __restrict__ start8, int* __restrict__ row_start) {
  __shared__ int lds[1024];
  __shared__ int wsum[4];
  int blk = blockIdx.x, t = threadIdx.x, lane = t & 63, wid = t >> 6;
  const int* in;
  int* out;
  int base, n;
  if (blk < SCB_BIN) { in = cnt8em; out = start8; base = blk * 1024; n = NBIN; }
  else { in = row_cnt; out = row_start; base = (blk - SCB_BIN) * 1024; n = NGENES; }
  int coff = boff[blk];
#pragma unroll
  for (int k = 0; k < 4; ++k) {
    int e = t + k * 256;
    lds[e] = (base + e < n) ? in[base + e] : 0;
  }
  __syncthreads();
  int x0 = lds[4 * t], x1 = lds[4 * t + 1], x2 = lds[4 * t + 2], x3 = lds[4 * t + 3];
  int s = x0 + x1 + x2 + x3;
  int incl = wave_incl_scan(s);
  if (lane == 63) wsum[wid] = incl;
  __syncthreads();
  int woff = 0;
  for (int w = 0; w < wid; ++w) woff += wsum[w];
  int tb = coff + woff + incl - s;
  int i0 = base + 4 * t;
  if (i0 + 3 < n) {
    ((int4*)(out + i0))[0] = make_int4(tb, tb + x0, tb + x0 + x1, tb + x0 + x1 + x2);
  } else {
    if (i0 < n) out[i0] = tb;
    if (i0 + 1 < n) out[i0 + 1] = tb + x0;
    if (i0 + 2 < n) out[i0 + 2] = tb + x0 + x1;
    if (i0 + 3 < n) out[i0 + 3] = tb + x0 + x1 + x2;
  }
}

// MERGED placement. grid (NCH, 5), 1024 thr.
__global__ void k_place(const int* __restrict__ rows, const int* __restrict__ cols,
                        const float* __restrict__ vals, const float* __restrict__ dv_inv,
                        const int* __restrict__ start8, const int* __restrict__ ccpre8,
                        const int* __restrict__ row_start, int* __restrict__ row_cur,
                        const unsigned* __restrict__ bitmap,
                        int2* __restrict__ csc, int2* __restrict__ csr) {
  __shared__ char smem_raw[40000];
  int c = blockIdx.x, role = blockIdx.y, tid = threadIdx.x;
  int lo = c * (NNZ_C / NCH), hi = lo + (NNZ_C / NCH);
  if (role < 4) {
    int* cnt_s = (int*)smem_raw;
    for (int j = tid; j < 2 * NEDGES; j += 1024) cnt_s[j] = 0;
    __syncthreads();
    const int* cp = ccpre8 + (size_t)c * NBIN;
    for (int i = lo + tid; i < hi; i += 1024) {
      int r = rows[i];
      int t = r / TILESZ;
      if ((t >> 1) != role) continue;
      int e = cols[i];
      float w = vals[i] * dv_inv[r];
      int rank = atomicAdd(&cnt_s[(t & 1) * NEDGES + e], 1);
      int pos = start8[e * 8 + t] + cp[t * NEDGES + e] + rank;
      csc[pos] = make_int2(r, __float_as_int(w));
    }
  } else {
    unsigned* bm_s = (unsigned*)smem_raw;
    for (int j = tid; j < NBMW; j += 1024) bm_s[j] = bitmap[j];
    __syncthreads();
    for (int i = lo + tid; i < hi; i += 1024) {
      int r = rows[i];
      if ((bm_s[r >> 5] >> (r & 31)) & 1) {
        int p2 = row_start[r] + atomicAdd(row_cur + r, 1);
        if (p2 < CSRCAP) csr[p2] = make_int2(cols[i], __float_as_int(vals[i]));
      }
    }
  }
}

// XCD-affine tiled edge pass: block bid -> (e=bid>>3, tile t=bid&7).
__global__ void k_edge_t(const int* __restrict__ start8, const int* __restrict__ cnt8em,
                         const int2* __restrict__ csc, const float* __restrict__ ge,
                         float* __restrict__ part) {
  __shared__ float4 red[32];
  int bid = blockIdx.x;
  int s = start8[bid];
  int n = cnt8em[bid];
  int g = threadIdx.x >> 5, l = threadIdx.x & 31;
  float4 a0 = make_float4(0.f, 0.f, 0.f, 0.f);
  float4 a1 = make_float4(0.f, 0.f, 0.f, 0.f);
  float4 a2 = make_float4(0.f, 0.f, 0.f, 0.f);
  float4 a3 = make_float4(0.f, 0.f, 0.f, 0.f);
  int i = s + g;
  int end = s + n;
  for (; i + 6 < end; i += 8) {
    int2 e0 = csc[i];
    int2 e1 = csc[i + 2];
    int2 e2 = csc[i + 4];
    int2 e3 = csc[i + 6];
    float4 x0 = *((const float4*)(ge + (size_t)e0.x * DIM) + l);
    float4 x1 = *((const float4*)(ge + (size_t)e1.x * DIM) + l);
    float4 x2 = *((const float4*)(ge + (size_t)e2.x * DIM) + l);
    float4 x3 = *((const float4*)(ge + (size_t)e3.x * DIM) + l);
    float w0 = __int_as_float(e0.y), w1 = __int_as_float(e1.y);
    float w2 = __int_as_float(e2.y), w3 = __int_as_float(e3.y);
    a0.x += w0 * x0.x; a0.y += w0 * x0.y; a0.z += w0 * x0.z; a0.w += w0 * x0.w;
    a1.x += w1 * x1.x; a1.y += w1 * x1.y; a1.z += w1 * x1.z; a1.w += w1 * x1.w;
    a2.x += w2 * x2.x; a2.y += w2 * x2.y; a2.z += w2 * x2.z; a2.w += w2 * x2.w;
    a3.x += w3 * x3.x; a3.y += w3 * x3.y; a3.z += w3 * x3.z; a3.w += w3 * x3.w;
  }
  for (; i < end; i += 2) {
    int2 en = csc[i];
    float w = __int_as_float(en.y);
    float4 x = *((const float4*)(ge + (size_t)en.x * DIM) + l);
    a0.x += w * x.x; a0.y += w * x.y; a0.z += w * x.z; a0.w += w * x.w;
  }
  a0.x += a1.x + a2.x + a3.x;
  a0.y += a1.y + a2.y + a3.y;
  a0.z += a1.z + a2.z + a3.z;
  a0.w += a1.w + a2.w + a3.w;
  if (g == 1) red[l] = a0;
  __syncthreads();
  if (g == 0) {
    float4 b = red[l];
    a0.x += b.x; a0.y += b.y; a0.z += b.z; a0.w += b.w;
    *((float4*)(part + (size_t)bid * DIM) + l) = a0;
  }
}

// HXde[e,:] = de_inv[e] * sum_t part[e*8+t,:]
__global__ void k_edge_red(const float* __restrict__ part, const float* __restrict__ de_inv,
                           float* __restrict__ HXde) {
  int e = blockIdx.x, d = threadIdx.x;
  float s = 0.f;
#pragma unroll
  for (int t = 0; t < NT; ++t) s += part[((size_t)e * 8 + t) * DIM + d];
  HXde[(size_t)e * DIM + d] = s * de_inv[e];
}

// pass C fused with gene_ids gather; 4 groups, 2-deep unroll (proven form)
__global__ void k_gene(const int* __restrict__ gene_ids, const int* __restrict__ row_start,
                       const int* __restrict__ row_cnt, const int2* __restrict__ csr,
                       const float* __restrict__ HXde, const float* __restrict__ dv_inv,
                       float* __restrict__ Xg) {
  __shared__ float4 red[4][32];
  int bm = blockIdx.x;
  int gene = gene_ids[bm];
  int s = row_start[gene], n = row_cnt[gene];
  int end = s + n;
  int g = threadIdx.x >> 5, l = threadIdx.x & 31;
  float4 a0 = make_float4(0.f, 0.f, 0.f, 0.f);
  float4 a1 = make_float4(0.f, 0.f, 0.f, 0.f);
  int i = s + g;
  for (; i + 4 < end; i += 8) {
    int2 e0 = csr[i];
    int2 e1 = csr[i + 4];
    float4 x0 = *((const float4*)(HXde + (size_t)e0.x * DIM) + l);
    float4 x1 = *((const float4*)(HXde + (size_t)e1.x * DIM) + l);
    float v0 = __int_as_float(e0.y), v1 = __int_as_float(e1.y);
    a0.x += v0 * x0.x; a0.y += v0 * x0.y; a0.z += v0 * x0.z; a0.w += v0 * x0.w;
    a1.x += v1 * x1.x; a1.y += v1 * x1.y; a1.z += v1 * x1.z; a1.w += v1 * x1.w;
  }
  for (; i < end; i += 4) {
    int2 en = csr[i];
    float v = __int_as_float(en.y);
    float4 x = *((const float4*)(HXde + (size_t)en.x * DIM) + l);
    a0.x += v * x.x; a0.y += v * x.y; a0.z += v * x.z; a0.w += v * x.w;
  }
  a0.x += a1.x; a0.y += a1.y; a0.z += a1.z; a0.w += a1.w;
  red[g][l] = a0;
  __syncthreads();
  if (g == 0) {
    float4 a = red[0][l], b = red[1][l], c = red[2][l], d = red[3][l];
    float dvg = dv_inv[gene];
    float4 o;
    o.x = (a.x + b.x + c.x + d.x) * dvg;
    o.y = (a.y + b.y + c.y + d.y) * dvg;
    o.z = (a.z + b.z + c.z + d.z) * dvg;
    o.w = (a.w + b.w + c.w + d.w) * dvg;
    *((float4*)(Xg + (size_t)bm * DIM) + l) = o;
  }
}

// rep[b,p,d] = (sum_m Xg[b,m,d]*mask[m,p]) / max(cnt[p],1)
// packed-bit masks, BRANCHLESS select: sel = -(bit) as an AND-mask on the float.
// No conditionals -> no s_cbranch chains (R14's failure mode). Loads: 2 scalar
// dwords per m at sequential addresses (no dependent gather chain) + 1 Xg float.
#define PT 20
__global__ void k_pathway(const unsigned* __restrict__ pk,
                          const float* __restrict__ Xg, float* __restrict__ rep) {
  int b = blockIdx.y;
  int p0 = blockIdx.x * PT;
  int d = threadIdx.x;
  float acc[PT];
  int icnt[PT];
#pragma unroll
  for (int pp = 0; pp < PT; ++pp) { acc[pp] = 0.f; icnt[pp] = 0; }
  int w0 = p0 >> 5;
  int sh = p0 & 31;
  const float* Xb = Xg + (size_t)b * MM * DIM + d;
  const unsigned* pmb = pk + (size_t)b * MM * PKW;
  for (int m = 0; m < MM; ++m) {
    float x = Xb[(size_t)m * DIM];
    unsigned xu = __float_as_uint(x);
    const unsigned* pm = pmb + m * PKW;
    unsigned lo = pm[w0], hi = pm[w0 + 1];
    unsigned mk = sh ? ((lo >> sh) | (hi << (32 - sh))) : lo;
#pragma unroll
    for (int pp = 0; pp < PT; ++pp) {
      unsigned bit = (mk >> pp) & 1u;
      unsigned sel = 0u - bit;  // 0x0 or 0xFFFFFFFF, wave-uniform, branchless
      acc[pp] += __uint_as_float(xu & sel);
      icnt[pp] += (int)bit;
    }
  }
#pragma unroll
  for (int pp = 0; pp < PT; ++pp) {
    rep[((size_t)b * NPATH + p0 + pp) * DIM + d] = acc[pp] / fmaxf((float)icnt[pp], 1.f);
  }
}

// scores[b,p] = tanh(rep@W1_top + ctx@W1_bot + b1) @ W2 + b2   (ctxw inlined)
#define PT2 10
__global__ void k_attn(const float* __restrict__ rep, const int* __restrict__ context_ids,
                       const float* __restrict__ treatment_embed,
                       const float* __restrict__ W1, const float* __restrict__ b1,
                       const float* __restrict__ W2, const float* __restrict__ b2,
                       float* __restrict__ scores) {
  __shared__ float in_s[PT2][DIM];
  __shared__ float ctx_s[DIM];
  __shared__ float part[PT2][2];
  int b = blockIdx.y;
  int p0 = blockIdx.x * PT2;
  int j = threadIdx.x;
  int lane = j & 63, wid = j >> 6;
  ctx_s[j] = treatment_embed[context_ids[b] * DIM + j];
#pragma unroll
  for (int pp = 0; pp < PT2; ++pp)
    in_s[pp][j] = rep[((size_t)b * NPATH + p0 + pp) * DIM + j];
  __syncthreads();
  float base = b1[j];
  for (int k = 0; k < DIM; ++k) base += ctx_s[k] * W1[(DIM + k) * DIM + j];
  float acc[PT2];
#pragma unroll
  for (int pp = 0; pp < PT2; ++pp) acc[pp] = base;
  for (int k = 0; k < DIM; ++k) {
    float w1 = W1[k * DIM + j];
#pragma unroll
    for (int pp = 0; pp < PT2; ++pp) acc[pp] += in_s[pp][k] * w1;
  }
  float w2 = W2[j];
#pragma unroll
  for (int pp = 0; pp < PT2; ++pp) {
    float t = tanhf(acc[pp]) * w2;
    t = wred_sum(t);
    if (lane == 0) part[pp][wid] = t;
  }
  __syncthreads();
  if (j < PT2) scores[b * NPATH + p0 + j] = part[j][0] + part[j][1] + b2[0];
}

// softmax + z0 + z + risk, one block per b (128 threads)
__global__ void k_final(const float* __restrict__ scores, const float* __restrict__ rep,
                        const float* __restrict__ latent_W, const float* __restrict__ latent_b,
                        const float* __restrict__ risk_W, const float* __restrict__ risk_b,
                        float* __restrict__ out) {
  __shared__ float w_s[NPATH];
  __shared__ float z0_s[DIM];
  __shared__ float red_max[2], red_sum[2], red_risk[2];
  int b = blockIdx.x, t = threadIdx.x;
  int lane = t & 63, wid = t >> 6;
  float lmax = -3.4e38f;
  for (int p = t; p < NPATH; p += 128) {
    float s = scores[b * NPATH + p];
    w_s[p] = s;
    lmax = fmaxf(lmax, s);
  }
  lmax = wred_max(lmax);
  if (lane == 0) red_max[wid] = lmax;
  __syncthreads();
  float bmax = fmaxf(red_max[0], red_max[1]);
  float lsum = 0.f;
  for (int p = t; p < NPATH; p += 128) {
    float e = expf(w_s[p] - bmax);
    w_s[p] = e;
    lsum += e;
  }
  lsum = wred_sum(lsum);
  if (lane == 0) red_sum[wid] = lsum;
  __syncthreads();
  float inv = 1.f / (red_sum[0] + red_sum[1]);
  int d = t;
  const float* repb = rep + (size_t)b * NPATH * DIM + d;
  float z00 = 0.f, z01 = 0.f, z02 = 0.f, z03 = 0.f;
  for (int p = 0; p < NPATH; p += 4) {
    z00 += w_s[p] * repb[(size_t)p * DIM];
    z01 += w_s[p + 1] * repb[(size_t)(p + 1) * DIM];
    z02 += w_s[p + 2] * repb[(size_t)(p + 2) * DIM];
    z03 += w_s[p + 3] * repb[(size_t)(p + 3) * DIM];
  }
  float z0 = ((z00 + z01) + (z02 + z03)) * inv;
  z0_s[d] = z0;
  __syncthreads();
  float z = latent_b[t];
  for (int dd = 0; dd < DIM; ++dd) z += z0_s[dd] * latent_W[dd * DIM + t];
  out[BB + b * DIM + t] = z;
  float r = z * risk_W[t];
  r = wred_sum(r);
  if (lane == 0) red_risk[wid] = r;
  __syncthreads();
  if (t == 0) out[b] = red_risk[0] + red_risk[1] + risk_b[0];
}

extern "C" void kernel_launch(void* const* d_in, const int* in_sizes, int n_in,
                              void* d_out, int out_size, void* d_ws, size_t ws_size,
                              hipStream_t stream) {
  const int* gene_ids = (const int*)d_in[0];
  const int* context_ids = (const int*)d_in[1];
  const int* H_rows = (const int*)d_in[2];
  const int* H_cols = (const int*)d_in[3];
  const float* H_vals = (const float*)d_in[4];
  const float* gene_embed = (const float*)d_in[5];
  const float* treatment_embed = (const float*)d_in[6];
  const float* gene_pathway = (const float*)d_in[7];
  const float* W1 = (const float*)d_in[8];
  const float* b1 = (const float*)d_in[9];
  const float* W2 = (const float*)d_in[10];
  const float* b2 = (const float*)d_in[11];
  const float* latent_W = (const float*)d_in[12];
  const float* latent_b = (const float*)d_in[13];
  const float* risk_W = (const float*)d_in[14];
  const float* risk_b = (const float*)d_in[15];
  float* out = (float*)d_out;

  char* ws = (char*)d_ws;
  // --- meta ---
  float* dv_inv = (float*)(ws + 0);             // -> 200000
  float* de_inv = (float*)(ws + 200000);        // -> 220000
  int* row_cnt = (int*)(ws + 220000);           // -> 420000
  int* row_start = (int*)(ws + 420000);         // -> 620000
  int* cnt8em = (int*)(ws + 620000);            // [e][t] 40000 -> 780000
  int* start8 = (int*)(ws + 780000);            // [e][t] 40000 -> 940000
  int* ccpre8 = (int*)(ws + 940000);            // [32][40000] -> 6060000
  float* scores = (float*)(ws + 6060000);       // -> 6188000
  int* bsum = (int*)(ws + 6220800);             // 89 -> pad 6221824
  int* boff = (int*)(ws + 6221824);             // 89 -> pad 6222848
  // --- memset zone ---
  int* row_cur = (int*)(ws + 6349824);          // -> 6549824
  unsigned* bitmap = (unsigned*)(ws + 6549824); // -> 6556096
  // --- sparse structures (written after k_reduce) ---
  int2* csc = (int2*)(ws + 6556096);            // 12.8M -> 19356096
  int2* csr = (int2*)(ws + 19356096);           // 3.2M -> 22556096
  float* HXde = (float*)(ws + 22556096);        // 2.56M -> 25116096
  float* part = (float*)(ws + 25116096);        // [40000][128]f 20.48M -> 45596096
  // --- hist partials ALIAS csc/csr/HXde/part-head (dead after k_reduce) ---
  float* pdv = (float*)(ws + 6556096);          // 32*50048*4 -> 12962240
  int* pcnt = (int*)(ws + 12962240);            // 32*50048*4 -> 19368384
  int* pbc = (int*)(ws + 19368384);             // 32*40000*4 -> 24488384
  float* pde = (float*)(ws + 24488384);         // 32*4*5000*4 -> 27048384
  // --- Xg/rep ALIAS part (part dead after k_edge_red) ---
  float* Xg = (float*)(ws + 25116096);          // 6.55M -> 31669696
  float* rep = (float*)(ws + 31669696);         // 16.38M -> 48053696
  // --- packed pathway masks (fresh region) ---
  unsigned* pk = (unsigned*)(ws + 48053696);    // 12800*17*4 = 870400 -> 48924096 (peak 48.92MB)

  hipMemsetAsync(ws + 6349824, 0, 206272, stream);  // row_cur + bitmap

  k_mark<<<(BMN + 255) / 256, 256, 0, stream>>>(gene_ids, bitmap);
  k_pack<<<(BMN + 3) / 4, 256, 0, stream>>>(gene_ids, gene_pathway, pk);
  k_build<<<dim3(NCH, 12), 1024, 0, stream>>>(H_rows, H_cols, H_vals, bitmap,
                                              pdv, pcnt, pbc, pde);
  k_reduce<<<(RED_N + 255) / 256, 256, 0, stream>>>(pdv, pcnt, pbc, pde, dv_inv, row_cnt,
                                                    ccpre8, cnt8em, de_inv);
  k_sc1<<<SCB, 256, 0, stream>>>(cnt8em, row_cnt, bsum);
  k_sc2<<<1, 128, 0, stream>>>(bsum, boff);
  k_sc3<<<SCB, 256, 0, stream>>>(cnt8em, row_cnt, boff, start8, row_start);
  k_place<<<dim3(NCH, 5), 1024, 0, stream>>>(H_rows, H_cols, H_vals, dv_inv,
                                             start8, ccpre8, row_start, row_cur,
                                             bitmap, csc, csr);
  k_edge_t<<<NBIN, 64, 0, stream>>>(start8, cnt8em, csc, gene_embed, part);
  k_edge_red<<<NEDGES, DIM, 0, stream>>>(part, de_inv, HXde);
  k_gene<<<BMN, 128, 0, stream>>>(gene_ids, row_start, row_cnt, csr, HXde, dv_inv, Xg);
  k_pathway<<<dim3(NPATH / PT, BB), DIM, 0, stream>>>(pk, Xg, rep);
  k_attn<<<dim3(NPATH / PT2, BB), DIM, 0, stream>>>(rep, context_ids, treatment_embed,
                                                    W1, b1, W2, b2, scores);
  k_final<<<BB, DIM, 0, stream>>>(scores, rep, latent_W, latent_b, risk_W, risk_b, out);
}

// Round 16
// 533.086 us; speedup vs baseline: 1.2575x; 1.2575x over previous
//
#include <hip/hip_runtime.h>
#include <math.h>

#define NGENES 50000
#define NEDGES 5000
#define NNZ_C 1600000
#define NPATH 500
#define DIM 128
#define BB 64
#define MM 200
#define BMN (BB * MM)
#define NBMW 1568          // bitmap words (50176 bits >= 50000)
#define CSRCAP 400000      // marked CSR entries ~362K expected
#define NCH 32             // chunks (hist + placement, must match ccpre8)
#define RNG 12512          // gene range per row-hist role (4*12512 = 50048)
#define GSTRIDE 50048      // row partial stride
#define NT 8               // gene tiles (one per XCD)
#define TILESZ 6250        // genes per tile -> 3.2 MB of gene_embed per tile
#define NBIN (NT * NEDGES) // 40000 (tile,edge) bins
#define BIN0 50048         // k_reduce index segments
#define EDGE0 90048
#define RED_N 95048
#define SCB_BIN 40         // scan chunk-blocks for bins (40*1024 >= 40000)
#define SCB_ROW 49         // scan chunk-blocks for rows (49*1024 >= 50000)
#define SCB (SCB_BIN + SCB_ROW)

// ---------------- wave helpers ----------------
__device__ inline float wred_sum(float x) {
#pragma unroll
  for (int off = 32; off > 0; off >>= 1) x += __shfl_down(x, off, 64);
  return x;
}
__device__ inline int wred_sumi(int x) {
#pragma unroll
  for (int off = 32; off > 0; off >>= 1) x += __shfl_down(x, off, 64);
  return x;
}
__device__ inline float wred_max(float x) {
#pragma unroll
  for (int off = 32; off > 0; off >>= 1) x = fmaxf(x, __shfl_down(x, off, 64));
  return x;
}
__device__ inline int wave_incl_scan(int x) {
  int lane = threadIdx.x & 63;
#pragma unroll
  for (int off = 1; off < 64; off <<= 1) {
    int y = __shfl_up(x, off, 64);
    if (lane >= off) x += y;
  }
  return x;
}

// mark genes referenced by gene_ids in a bitmap
__global__ void k_mark(const int* __restrict__ gene_ids, unsigned* __restrict__ bitmap) {
  int i = blockIdx.x * blockDim.x + threadIdx.x;
  if (i >= BMN) return;
  int g = gene_ids[i];
  atomicOr(bitmap + (g >> 5), 1u << (g & 31));
}

// MERGED build histograms, atomic-free. grid (NCH, 12), 1024 thr.
// roles 0-3 : Dv fp32 LDS hist over gene range [role*RNG,+RNG)
// roles 4-7 : marked-gene count hist over same ranges
// roles 8-11: (tile,edge) bin counts for tile-pair p=role-8 + De partial sums
__global__ void k_build(const int* __restrict__ rows, const int* __restrict__ cols,
                        const float* __restrict__ vals, const unsigned* __restrict__ bitmap,
                        float* __restrict__ pdv, int* __restrict__ pcnt,
                        int* __restrict__ pbc, float* __restrict__ pde) {
  __shared__ char smem_raw[60000];
  int c = blockIdx.x, role = blockIdx.y, tid = threadIdx.x;
  int lo = c * (NNZ_C / NCH), hi = lo + (NNZ_C / NCH);
  if (role < 4) {
    float* hs = (float*)smem_raw;
    int rlo = role * RNG;
    for (int j = tid; j < RNG; j += 1024) hs[j] = 0.f;
    __syncthreads();
    for (int i = lo + tid; i < hi; i += 1024) {
      int r = rows[i];
      unsigned d = (unsigned)(r - rlo);
      if (d < RNG) atomicAdd(&hs[d], vals[i]);
    }
    __syncthreads();
    float* dst = pdv + (size_t)c * GSTRIDE + rlo;
    for (int j = tid; j < RNG; j += 1024) dst[j] = hs[j];
  } else if (role < 8) {
    int* hs = (int*)smem_raw;
    unsigned* bm = (unsigned*)(smem_raw + RNG * 4);
    int rlo = (role - 4) * RNG;
    for (int j = tid; j < RNG; j += 1024) hs[j] = 0;
    for (int j = tid; j < NBMW; j += 1024) bm[j] = bitmap[j];
    __syncthreads();
    for (int i = lo + tid; i < hi; i += 1024) {
      int r = rows[i];
      unsigned d = (unsigned)(r - rlo);
      if (d < RNG && ((bm[r >> 5] >> (r & 31)) & 1)) atomicAdd(&hs[d], 1);
    }
    __syncthreads();
    int* dst = pcnt + (size_t)c * GSTRIDE + rlo;
    for (int j = tid; j < RNG; j += 1024) dst[j] = hs[j];
  } else {
    int p = role - 8;
    int* hc = (int*)smem_raw;                    // 40000 B
    float* hs = (float*)(smem_raw + 40000);      // 20000 B
    for (int j = tid; j < 2 * NEDGES; j += 1024) hc[j] = 0;
    for (int j = tid; j < NEDGES; j += 1024) hs[j] = 0.f;
    __syncthreads();
    for (int i = lo + tid; i < hi; i += 1024) {
      int r = rows[i];
      int t = r / TILESZ;
      if ((t >> 1) != p) continue;
      int e = cols[i];
      atomicAdd(&hc[(t & 1) * NEDGES + e], 1);
      atomicAdd(&hs[e], vals[i]);
    }
    __syncthreads();
    for (int j = tid; j < 2 * NEDGES; j += 1024) {
      int h = j / NEDGES, e = j - h * NEDGES;
      pbc[(size_t)c * NBIN + (2 * p + h) * NEDGES + e] = hc[j];
    }
    for (int j = tid; j < NEDGES; j += 1024)
      pde[((size_t)c * 4 + p) * NEDGES + j] = hs[j];
  }
}

// merged reduce: genes -> dv_inv,row_cnt; bins -> ccpre8 + edge-major cnt8em; edges -> de_inv
__global__ void k_reduce(const float* __restrict__ pdv, const int* __restrict__ pcnt,
                         const int* __restrict__ pbc, const float* __restrict__ pde,
                         float* __restrict__ dv_inv, int* __restrict__ row_cnt,
                         int* __restrict__ ccpre8, int* __restrict__ cnt8em,
                         float* __restrict__ de_inv) {
  int idx = blockIdx.x * 256 + threadIdx.x;
  if (idx < NGENES) {
    float s = 0.f;
    int n = 0;
    for (int c = 0; c < NCH; ++c) {
      s += pdv[(size_t)c * GSTRIDE + idx];
      n += pcnt[(size_t)c * GSTRIDE + idx];
    }
    dv_inv[idx] = 1.f / sqrtf(s + 1e-6f);
    row_cnt[idx] = n;
  } else if (idx >= BIN0 && idx < BIN0 + NBIN) {
    int b = idx - BIN0;  // tile-major bin id
    int t = b / NEDGES, e = b - t * NEDGES;
    int run = 0;
    for (int c = 0; c < NCH; ++c) {
      ccpre8[(size_t)c * NBIN + b] = run;
      run += pbc[(size_t)c * NBIN + b];
    }
    cnt8em[(e << 3) | t] = run;  // edge-major total (scan order)
  } else if (idx >= EDGE0 && idx < EDGE0 + NEDGES) {
    int e = idx - EDGE0;
    float s = 0.f;
    for (int cp = 0; cp < NCH * 4; ++cp) s += pde[(size_t)cp * NEDGES + e];
    de_inv[e] = 1.f / (s + 1e-6f);
  }
}

// ---- hierarchical coalesced scans over cnt8em (40000) and row_cnt (50000) ----
__global__ void k_sc1(const int* __restrict__ cnt8em, const int* __restrict__ row_cnt,
                      int* __restrict__ bsum) {
  __shared__ int wsum[4];
  int blk = blockIdx.x, t = threadIdx.x, lane = t & 63, wid = t >> 6;
  const int* in;
  int base, n;
  if (blk < SCB_BIN) { in = cnt8em; base = blk * 1024; n = NBIN; }
  else { in = row_cnt; base = (blk - SCB_BIN) * 1024; n = NGENES; }
  int s = 0;
#pragma unroll
  for (int k = 0; k < 4; ++k) {
    int e = base + t + k * 256;
    if (e < n) s += in[e];
  }
  s = wred_sumi(s);
  if (lane == 0) wsum[wid] = s;
  __syncthreads();
  if (t == 0) bsum[blk] = wsum[0] + wsum[1] + wsum[2] + wsum[3];
}

__global__ void k_sc2(const int* __restrict__ bsum, int* __restrict__ boff) {
  int t = threadIdx.x, lane = t & 63, wid = t >> 6;
  if (wid == 0) {
    int x = (lane < SCB_BIN) ? bsum[lane] : 0;
    int incl = wave_incl_scan(x);
    if (lane < SCB_BIN) boff[lane] = incl - x;
  } else {
    int x = (lane < SCB_ROW) ? bsum[SCB_BIN + lane] : 0;
    int incl = wave_incl_scan(x);
    if (lane < SCB_ROW) boff[SCB_BIN + lane] = incl - x;
  }
}

__global__ void k_sc3(const int* __restrict__ cnt8em, const int* __restrict__ row_cnt,
                      const int* __restrict__ boff,
                      int* __restrict__ start8, int* __restrict__ row_start) {
  __shared__ int lds[1024];
  __shared__ int wsum[4];
  int blk = blockIdx.x, t = threadIdx.x, lane = t & 63, wid = t >> 6;
  const int* in;
  int* out;
  int base, n;
  if (blk < SCB_BIN) { in = cnt8em; out = start8; base = blk * 1024; n = NBIN; }
  else { in = row_cnt; out = row_start; base = (blk - SCB_BIN) * 1024; n = NGENES; }
  int coff = boff[blk];
#pragma unroll
  for (int k = 0; k < 4; ++k) {
    int e = t + k * 256;
    lds[e] = (base + e < n) ? in[base + e] : 0;
  }
  __syncthreads();
  int x0 = lds[4 * t], x1 = lds[4 * t + 1], x2 = lds[4 * t + 2], x3 = lds[4 * t + 3];
  int s = x0 + x1 + x2 + x3;
  int incl = wave_incl_scan(s);
  if (lane == 63) wsum[wid] = incl;
  __syncthreads();
  int woff = 0;
  for (int w = 0; w < wid; ++w) woff += wsum[w];
  int tb = coff + woff + incl - s;
  int i0 = base + 4 * t;
  if (i0 + 3 < n) {
    ((int4*)(out + i0))[0] = make_int4(tb, tb + x0, tb + x0 + x1, tb + x0 + x1 + x2);
  } else {
    if (i0 < n) out[i0] = tb;
    if (i0 + 1 < n) out[i0 + 1] = tb + x0;
    if (i0 + 2 < n) out[i0 + 2] = tb + x0 + x1;
    if (i0 + 3 < n) out[i0 + 3] = tb + x0 + x1 + x2;
  }
}

// MERGED placement. grid (NCH, 5), 1024 thr.
// roles 0-3: CSC into (edge,tile)-ordered layout for tile-pair p=role (zero global
//            atomics, dv folded in). role 4: CSR for marked rows (~362K atomics).
__global__ void k_place(const int* __restrict__ rows, const int* __restrict__ cols,
                        const float* __restrict__ vals, const float* __restrict__ dv_inv,
                        const int* __restrict__ start8, const int* __restrict__ ccpre8,
                        const int* __restrict__ row_start, int* __restrict__ row_cur,
                        const unsigned* __restrict__ bitmap,
                        int2* __restrict__ csc, int2* __restrict__ csr) {
  __shared__ char smem_raw[40000];
  int c = blockIdx.x, role = blockIdx.y, tid = threadIdx.x;
  int lo = c * (NNZ_C / NCH), hi = lo + (NNZ_C / NCH);
  if (role < 4) {
    int* cnt_s = (int*)smem_raw;  // 2*NEDGES ints = 40000 B
    for (int j = tid; j < 2 * NEDGES; j += 1024) cnt_s[j] = 0;
    __syncthreads();
    const int* cp = ccpre8 + (size_t)c * NBIN;
    for (int i = lo + tid; i < hi; i += 1024) {
      int r = rows[i];
      int t = r / TILESZ;
      if ((t >> 1) != role) continue;
      int e = cols[i];
      float w = vals[i] * dv_inv[r];
      int rank = atomicAdd(&cnt_s[(t & 1) * NEDGES + e], 1);
      int pos = start8[e * 8 + t] + cp[t * NEDGES + e] + rank;
      csc[pos] = make_int2(r, __float_as_int(w));
    }
  } else {
    unsigned* bm_s = (unsigned*)smem_raw;  // 6272 B
    for (int j = tid; j < NBMW; j += 1024) bm_s[j] = bitmap[j];
    __syncthreads();
    for (int i = lo + tid; i < hi; i += 1024) {
      int r = rows[i];
      if ((bm_s[r >> 5] >> (r & 31)) & 1) {
        int p2 = row_start[r] + atomicAdd(row_cur + r, 1);
        if (p2 < CSRCAP) csr[p2] = make_int2(cols[i], __float_as_int(vals[i]));
      }
    }
  }
}

// XCD-affine tiled edge pass: block bid -> (e=bid>>3, tile t=bid&7).
__global__ void k_edge_t(const int* __restrict__ start8, const int* __restrict__ cnt8em,
                         const int2* __restrict__ csc, const float* __restrict__ ge,
                         float* __restrict__ part) {
  __shared__ float4 red[32];
  int bid = blockIdx.x;
  int s = start8[bid];
  int n = cnt8em[bid];
  int g = threadIdx.x >> 5, l = threadIdx.x & 31;
  float4 a0 = make_float4(0.f, 0.f, 0.f, 0.f);
  float4 a1 = make_float4(0.f, 0.f, 0.f, 0.f);
  float4 a2 = make_float4(0.f, 0.f, 0.f, 0.f);
  float4 a3 = make_float4(0.f, 0.f, 0.f, 0.f);
  int i = s + g;
  int end = s + n;
  for (; i + 6 < end; i += 8) {
    int2 e0 = csc[i];
    int2 e1 = csc[i + 2];
    int2 e2 = csc[i + 4];
    int2 e3 = csc[i + 6];
    float4 x0 = *((const float4*)(ge + (size_t)e0.x * DIM) + l);
    float4 x1 = *((const float4*)(ge + (size_t)e1.x * DIM) + l);
    float4 x2 = *((const float4*)(ge + (size_t)e2.x * DIM) + l);
    float4 x3 = *((const float4*)(ge + (size_t)e3.x * DIM) + l);
    float w0 = __int_as_float(e0.y), w1 = __int_as_float(e1.y);
    float w2 = __int_as_float(e2.y), w3 = __int_as_float(e3.y);
    a0.x += w0 * x0.x; a0.y += w0 * x0.y; a0.z += w0 * x0.z; a0.w += w0 * x0.w;
    a1.x += w1 * x1.x; a1.y += w1 * x1.y; a1.z += w1 * x1.z; a1.w += w1 * x1.w;
    a2.x += w2 * x2.x; a2.y += w2 * x2.y; a2.z += w2 * x2.z; a2.w += w2 * x2.w;
    a3.x += w3 * x3.x; a3.y += w3 * x3.y; a3.z += w3 * x3.z; a3.w += w3 * x3.w;
  }
  for (; i < end; i += 2) {
    int2 en = csc[i];
    float w = __int_as_float(en.y);
    float4 x = *((const float4*)(ge + (size_t)en.x * DIM) + l);
    a0.x += w * x.x; a0.y += w * x.y; a0.z += w * x.z; a0.w += w * x.w;
  }
  a0.x += a1.x + a2.x + a3.x;
  a0.y += a1.y + a2.y + a3.y;
  a0.z += a1.z + a2.z + a3.z;
  a0.w += a1.w + a2.w + a3.w;
  if (g == 1) red[l] = a0;
  __syncthreads();
  if (g == 0) {
    float4 b = red[l];
    a0.x += b.x; a0.y += b.y; a0.z += b.z; a0.w += b.w;
    *((float4*)(part + (size_t)bid * DIM) + l) = a0;
  }
}

// HXde[e,:] = de_inv[e] * sum_t part[e*8+t,:]
__global__ void k_edge_red(const float* __restrict__ part, const float* __restrict__ de_inv,
                           float* __restrict__ HXde) {
  int e = blockIdx.x, d = threadIdx.x;
  float s = 0.f;
#pragma unroll
  for (int t = 0; t < NT; ++t) s += part[((size_t)e * 8 + t) * DIM + d];
  HXde[(size_t)e * DIM + d] = s * de_inv[e];
}

// pass C fused with gene_ids gather; 4 groups, 2-deep unroll (proven form)
__global__ void k_gene(const int* __restrict__ gene_ids, const int* __restrict__ row_start,
                       const int* __restrict__ row_cnt, const int2* __restrict__ csr,
                       const float* __restrict__ HXde, const float* __restrict__ dv_inv,
                       float* __restrict__ Xg) {
  __shared__ float4 red[4][32];
  int bm = blockIdx.x;
  int gene = gene_ids[bm];
  int s = row_start[gene], n = row_cnt[gene];
  int end = s + n;
  int g = threadIdx.x >> 5, l = threadIdx.x & 31;
  float4 a0 = make_float4(0.f, 0.f, 0.f, 0.f);
  float4 a1 = make_float4(0.f, 0.f, 0.f, 0.f);
  int i = s + g;
  for (; i + 4 < end; i += 8) {
    int2 e0 = csr[i];
    int2 e1 = csr[i + 4];
    float4 x0 = *((const float4*)(HXde + (size_t)e0.x * DIM) + l);
    float4 x1 = *((const float4*)(HXde + (size_t)e1.x * DIM) + l);
    float v0 = __int_as_float(e0.y), v1 = __int_as_float(e1.y);
    a0.x += v0 * x0.x; a0.y += v0 * x0.y; a0.z += v0 * x0.z; a0.w += v0 * x0.w;
    a1.x += v1 * x1.x; a1.y += v1 * x1.y; a1.z += v1 * x1.z; a1.w += v1 * x1.w;
  }
  for (; i < end; i += 4) {
    int2 en = csr[i];
    float v = __int_as_float(en.y);
    float4 x = *((const float4*)(HXde + (size_t)en.x * DIM) + l);
    a0.x += v * x.x; a0.y += v * x.y; a0.z += v * x.z; a0.w += v * x.w;
  }
  a0.x += a1.x; a0.y += a1.y; a0.z += a1.z; a0.w += a1.w;
  red[g][l] = a0;
  __syncthreads();
  if (g == 0) {
    float4 a = red[0][l], b = red[1][l], c = red[2][l], d = red[3][l];
    float dvg = dv_inv[gene];
    float4 o;
    o.x = (a.x + b.x + c.x + d.x) * dvg;
    o.y = (a.y + b.y + c.y + d.y) * dvg;
    o.z = (a.z + b.z + c.z + d.z) * dvg;
    o.w = (a.w + b.w + c.w + d.w) * dvg;
    *((float4*)(Xg + (size_t)bm * DIM) + l) = o;
  }
}

// rep[b,p,d] = (sum_m Xg[b,m,d]*mask[m,p]) / max(cnt[p],1)
// R12-proven dense form (wave-uniform mask rows -> wide scalar loads; 2 VALU per
// pathway). Only change vs R12: unroll 2 on the m loop so two mask-row wide
// s_loads are in flight (the gid loads are sequential/independent).
#define PT 20
__global__ void k_pathway(const int* __restrict__ gene_ids,
                          const float* __restrict__ gene_pathway,
                          const float* __restrict__ Xg, float* __restrict__ rep) {
  int b = blockIdx.y;
  int p0 = blockIdx.x * PT;
  int d = threadIdx.x;
  float acc[PT], cnt[PT];
#pragma unroll
  for (int pp = 0; pp < PT; ++pp) { acc[pp] = 0.f; cnt[pp] = 0.f; }
#pragma unroll 2
  for (int m = 0; m < MM; ++m) {
    int g = gene_ids[b * MM + m];
    float x = Xg[(size_t)(b * MM + m) * DIM + d];
    const float* mrow = gene_pathway + (size_t)g * NPATH + p0;
#pragma unroll
    for (int pp = 0; pp < PT; ++pp) {
      float mv = mrow[pp];
      acc[pp] += mv * x;
      cnt[pp] += mv;
    }
  }
#pragma unroll
  for (int pp = 0; pp < PT; ++pp) {
    rep[((size_t)b * NPATH + p0 + pp) * DIM + d] = acc[pp] / fmaxf(cnt[pp], 1.f);
  }
}

// scores[b,p] = tanh(rep@W1_top + ctx@W1_bot + b1) @ W2 + b2   (ctxw inlined)
#define PT2 10
__global__ void k_attn(const float* __restrict__ rep, const int* __restrict__ context_ids,
                       const float* __restrict__ treatment_embed,
                       const float* __restrict__ W1, const float* __restrict__ b1,
                       const float* __restrict__ W2, const float* __restrict__ b2,
                       float* __restrict__ scores) {
  __shared__ float in_s[PT2][DIM];
  __shared__ float ctx_s[DIM];
  __shared__ float part[PT2][2];
  int b = blockIdx.y;
  int p0 = blockIdx.x * PT2;
  int j = threadIdx.x;
  int lane = j & 63, wid = j >> 6;
  ctx_s[j] = treatment_embed[context_ids[b] * DIM + j];
#pragma unroll
  for (int pp = 0; pp < PT2; ++pp)
    in_s[pp][j] = rep[((size_t)b * NPATH + p0 + pp) * DIM + j];
  __syncthreads();
  float base = b1[j];
  for (int k = 0; k < DIM; ++k) base += ctx_s[k] * W1[(DIM + k) * DIM + j];
  float acc[PT2];
#pragma unroll
  for (int pp = 0; pp < PT2; ++pp) acc[pp] = base;
  for (int k = 0; k < DIM; ++k) {
    float w1 = W1[k * DIM + j];
#pragma unroll
    for (int pp = 0; pp < PT2; ++pp) acc[pp] += in_s[pp][k] * w1;
  }
  float w2 = W2[j];
#pragma unroll
  for (int pp = 0; pp < PT2; ++pp) {
    float t = tanhf(acc[pp]) * w2;
    t = wred_sum(t);
    if (lane == 0) part[pp][wid] = t;
  }
  __syncthreads();
  if (j < PT2) scores[b * NPATH + p0 + j] = part[j][0] + part[j][1] + b2[0];
}

// softmax + z0 + z + risk, one block per b (128 threads)
__global__ void k_final(const float* __restrict__ scores, const float* __restrict__ rep,
                        const float* __restrict__ latent_W, const float* __restrict__ latent_b,
                        const float* __restrict__ risk_W, const float* __restrict__ risk_b,
                        float* __restrict__ out) {
  __shared__ float w_s[NPATH];
  __shared__ float z0_s[DIM];
  __shared__ float red_max[2], red_sum[2], red_risk[2];
  int b = blockIdx.x, t = threadIdx.x;
  int lane = t & 63, wid = t >> 6;
  float lmax = -3.4e38f;
  for (int p = t; p < NPATH; p += 128) {
    float s = scores[b * NPATH + p];
    w_s[p] = s;
    lmax = fmaxf(lmax, s);
  }
  lmax = wred_max(lmax);
  if (lane == 0) red_max[wid] = lmax;
  __syncthreads();
  float bmax = fmaxf(red_max[0], red_max[1]);
  float lsum = 0.f;
  for (int p = t; p < NPATH; p += 128) {
    float e = expf(w_s[p] - bmax);
    w_s[p] = e;
    lsum += e;
  }
  lsum = wred_sum(lsum);
  if (lane == 0) red_sum[wid] = lsum;
  __syncthreads();
  float inv = 1.f / (red_sum[0] + red_sum[1]);
  int d = t;
  const float* repb = rep + (size_t)b * NPATH * DIM + d;
  float z00 = 0.f, z01 = 0.f, z02 = 0.f, z03 = 0.f;
  for (int p = 0; p < NPATH; p += 4) {
    z00 += w_s[p] * repb[(size_t)p * DIM];
    z01 += w_s[p + 1] * repb[(size_t)(p + 1) * DIM];
    z02 += w_s[p + 2] * repb[(size_t)(p + 2) * DIM];
    z03 += w_s[p + 3] * repb[(size_t)(p + 3) * DIM];
  }
  float z0 = ((z00 + z01) + (z02 + z03)) * inv;
  z0_s[d] = z0;
  __syncthreads();
  float z = latent_b[t];
  for (int dd = 0; dd < DIM; ++dd) z += z0_s[dd] * latent_W[dd * DIM + t];
  out[BB + b * DIM + t] = z;
  float r = z * risk_W[t];
  r = wred_sum(r);
  if (lane == 0) red_risk[wid] = r;
  __syncthreads();
  if (t == 0) out[b] = red_risk[0] + red_risk[1] + risk_b[0];
}

extern "C" void kernel_launch(void* const* d_in, const int* in_sizes, int n_in,
                              void* d_out, int out_size, void* d_ws, size_t ws_size,
                              hipStream_t stream) {
  const int* gene_ids = (const int*)d_in[0];
  const int* context_ids = (const int*)d_in[1];
  const int* H_rows = (const int*)d_in[2];
  const int* H_cols = (const int*)d_in[3];
  const float* H_vals = (const float*)d_in[4];
  const float* gene_embed = (const float*)d_in[5];
  const float* treatment_embed = (const float*)d_in[6];
  const float* gene_pathway = (const float*)d_in[7];
  const float* W1 = (const float*)d_in[8];
  const float* b1 = (const float*)d_in[9];
  const float* W2 = (const float*)d_in[10];
  const float* b2 = (const float*)d_in[11];
  const float* latent_W = (const float*)d_in[12];
  const float* latent_b = (const float*)d_in[13];
  const float* risk_W = (const float*)d_in[14];
  const float* risk_b = (const float*)d_in[15];
  float* out = (float*)d_out;

  char* ws = (char*)d_ws;
  // --- meta ---
  float* dv_inv = (float*)(ws + 0);             // -> 200000
  float* de_inv = (float*)(ws + 200000);        // -> 220000
  int* row_cnt = (int*)(ws + 220000);           // -> 420000
  int* row_start = (int*)(ws + 420000);         // -> 620000
  int* cnt8em = (int*)(ws + 620000);            // [e][t] 40000 -> 780000
  int* start8 = (int*)(ws + 780000);            // [e][t] 40000 -> 940000
  int* ccpre8 = (int*)(ws + 940000);            // [32][40000] -> 6060000
  float* scores = (float*)(ws + 6060000);       // -> 6188000
  int* bsum = (int*)(ws + 6220800);             // 89 -> pad 6221312
  int* boff = (int*)(ws + 6221312);             // 89 -> pad 6221824
  // --- memset zone ---
  int* row_cur = (int*)(ws + 6349824);          // -> 6549824
  unsigned* bitmap = (unsigned*)(ws + 6549824); // -> 6556096
  // --- sparse structures (written after k_reduce) ---
  int2* csc = (int2*)(ws + 6556096);            // 12.8M -> 19356096
  int2* csr = (int2*)(ws + 19356096);           // 3.2M -> 22556096
  float* HXde = (float*)(ws + 22556096);        // 2.56M -> 25116096
  float* part = (float*)(ws + 25116096);        // [40000][128]f 20.48M -> 45596096
  // --- hist partials ALIAS csc/csr/HXde/part-head (dead after k_reduce) ---
  float* pdv = (float*)(ws + 6556096);          // 32*50048*4 -> 12962240
  int* pcnt = (int*)(ws + 12962240);            // 32*50048*4 -> 19368384
  int* pbc = (int*)(ws + 19368384);             // 32*40000*4 -> 24488384
  float* pde = (float*)(ws + 24488384);         // 32*4*5000*4 -> 27048384
  // --- Xg/rep ALIAS part (part dead after k_edge_red) ---
  float* Xg = (float*)(ws + 25116096);          // 6.55M -> 31669696
  float* rep = (float*)(ws + 31669696);         // 16.38M -> 48053696 (peak 48.05MB)

  hipMemsetAsync(ws + 6349824, 0, 206272, stream);  // row_cur + bitmap

  k_mark<<<(BMN + 255) / 256, 256, 0, stream>>>(gene_ids, bitmap);
  k_build<<<dim3(NCH, 12), 1024, 0, stream>>>(H_rows, H_cols, H_vals, bitmap,
                                              pdv, pcnt, pbc, pde);
  k_reduce<<<(RED_N + 255) / 256, 256, 0, stream>>>(pdv, pcnt, pbc, pde, dv_inv, row_cnt,
                                                    ccpre8, cnt8em, de_inv);
  k_sc1<<<SCB, 256, 0, stream>>>(cnt8em, row_cnt, bsum);
  k_sc2<<<1, 128, 0, stream>>>(bsum, boff);
  k_sc3<<<SCB, 256, 0, stream>>>(cnt8em, row_cnt, boff, start8, row_start);
  k_place<<<dim3(NCH, 5), 1024, 0, stream>>>(H_rows, H_cols, H_vals, dv_inv,
                                             start8, ccpre8, row_start, row_cur,
                                             bitmap, csc, csr);
  k_edge_t<<<NBIN, 64, 0, stream>>>(start8, cnt8em, csc, gene_embed, part);
  k_edge_red<<<NEDGES, DIM, 0, stream>>>(part, de_inv, HXde);
  k_gene<<<BMN, 128, 0, stream>>>(gene_ids, row_start, row_cnt, csr, HXde, dv_inv, Xg);
  k_pathway<<<dim3(NPATH / PT, BB), DIM, 0, stream>>>(gene_ids, gene_pathway, Xg, rep);
  k_attn<<<dim3(NPATH / PT2, BB), DIM, 0, stream>>>(rep, context_ids, treatment_embed,
                                                    W1, b1, W2, b2, scores);
  k_final<<<BB, DIM, 0, stream>>>(scores, rep, latent_W, latent_b, risk_W, risk_b, out);
}

// Round 17
// 501.735 us; speedup vs baseline: 1.3361x; 1.0625x over previous
//
#include <hip/hip_runtime.h>
#include <math.h>

#define NGENES 50000
#define NEDGES 5000
#define NNZ_C 1600000
#define NPATH 500
#define DIM 128
#define BB 64
#define MM 200
#define BMN (BB * MM)
#define NBMW 1568          // bitmap words (50176 bits >= 50000)
#define CSRCAP 400000      // marked CSR entries ~362K expected
#define NCH 32             // chunks (hist + placement, must match ccpre8)
#define RNG 12512          // gene range per row-hist role (4*12512 = 50048)
#define GSTRIDE 50048      // row partial stride
#define NT 8               // gene tiles (one per XCD)
#define TILESZ 6250        // genes per tile -> 3.2 MB of gene_embed per tile
#define NBIN (NT * NEDGES) // 40000 (tile,edge) bins
#define BIN0 50048         // k_reduce index segments
#define EDGE0 90048
#define RED_N 95048
#define SCB_BIN 40         // scan chunk-blocks for bins (40*1024 >= 40000)
#define SCB_ROW 49         // scan chunk-blocks for rows (49*1024 >= 50000)
#define SCB (SCB_BIN + SCB_ROW)

// ---------------- wave helpers ----------------
__device__ inline float wred_sum(float x) {
#pragma unroll
  for (int off = 32; off > 0; off >>= 1) x += __shfl_down(x, off, 64);
  return x;
}
__device__ inline int wred_sumi(int x) {
#pragma unroll
  for (int off = 32; off > 0; off >>= 1) x += __shfl_down(x, off, 64);
  return x;
}
__device__ inline float wred_max(float x) {
#pragma unroll
  for (int off = 32; off > 0; off >>= 1) x = fmaxf(x, __shfl_down(x, off, 64));
  return x;
}
__device__ inline int wave_incl_scan(int x) {
  int lane = threadIdx.x & 63;
#pragma unroll
  for (int off = 1; off < 64; off <<= 1) {
    int y = __shfl_up(x, off, 64);
    if (lane >= off) x += y;
  }
  return x;
}

// mark genes referenced by gene_ids in a bitmap
__global__ void k_mark(const int* __restrict__ gene_ids, unsigned* __restrict__ bitmap) {
  int i = blockIdx.x * blockDim.x + threadIdx.x;
  if (i >= BMN) return;
  int g = gene_ids[i];
  atomicOr(bitmap + (g >> 5), 1u << (g & 31));
}

// MERGED build histograms, atomic-free. grid (NCH, 12), 1024 thr.
__global__ void k_build(const int* __restrict__ rows, const int* __restrict__ cols,
                        const float* __restrict__ vals, const unsigned* __restrict__ bitmap,
                        float* __restrict__ pdv, int* __restrict__ pcnt,
                        int* __restrict__ pbc, float* __restrict__ pde) {
  __shared__ char smem_raw[60000];
  int c = blockIdx.x, role = blockIdx.y, tid = threadIdx.x;
  int lo = c * (NNZ_C / NCH), hi = lo + (NNZ_C / NCH);
  if (role < 4) {
    float* hs = (float*)smem_raw;
    int rlo = role * RNG;
    for (int j = tid; j < RNG; j += 1024) hs[j] = 0.f;
    __syncthreads();
    for (int i = lo + tid; i < hi; i += 1024) {
      int r = rows[i];
      unsigned d = (unsigned)(r - rlo);
      if (d < RNG) atomicAdd(&hs[d], vals[i]);
    }
    __syncthreads();
    float* dst = pdv + (size_t)c * GSTRIDE + rlo;
    for (int j = tid; j < RNG; j += 1024) dst[j] = hs[j];
  } else if (role < 8) {
    int* hs = (int*)smem_raw;
    unsigned* bm = (unsigned*)(smem_raw + RNG * 4);
    int rlo = (role - 4) * RNG;
    for (int j = tid; j < RNG; j += 1024) hs[j] = 0;
    for (int j = tid; j < NBMW; j += 1024) bm[j] = bitmap[j];
    __syncthreads();
    for (int i = lo + tid; i < hi; i += 1024) {
      int r = rows[i];
      unsigned d = (unsigned)(r - rlo);
      if (d < RNG && ((bm[r >> 5] >> (r & 31)) & 1)) atomicAdd(&hs[d], 1);
    }
    __syncthreads();
    int* dst = pcnt + (size_t)c * GSTRIDE + rlo;
    for (int j = tid; j < RNG; j += 1024) dst[j] = hs[j];
  } else {
    int p = role - 8;
    int* hc = (int*)smem_raw;                    // 40000 B
    float* hs = (float*)(smem_raw + 40000);      // 20000 B
    for (int j = tid; j < 2 * NEDGES; j += 1024) hc[j] = 0;
    for (int j = tid; j < NEDGES; j += 1024) hs[j] = 0.f;
    __syncthreads();
    for (int i = lo + tid; i < hi; i += 1024) {
      int r = rows[i];
      int t = r / TILESZ;
      if ((t >> 1) != p) continue;
      int e = cols[i];
      atomicAdd(&hc[(t & 1) * NEDGES + e], 1);
      atomicAdd(&hs[e], vals[i]);
    }
    __syncthreads();
    for (int j = tid; j < 2 * NEDGES; j += 1024) {
      int h = j / NEDGES, e = j - h * NEDGES;
      pbc[(size_t)c * NBIN + (2 * p + h) * NEDGES + e] = hc[j];
    }
    for (int j = tid; j < NEDGES; j += 1024)
      pde[((size_t)c * 4 + p) * NEDGES + j] = hs[j];
  }
}

// merged reduce: genes -> dv_inv,row_cnt; bins -> ccpre8 + edge-major cnt8em; edges -> de_inv
__global__ void k_reduce(const float* __restrict__ pdv, const int* __restrict__ pcnt,
                         const int* __restrict__ pbc, const float* __restrict__ pde,
                         float* __restrict__ dv_inv, int* __restrict__ row_cnt,
                         int* __restrict__ ccpre8, int* __restrict__ cnt8em,
                         float* __restrict__ de_inv) {
  int idx = blockIdx.x * 256 + threadIdx.x;
  if (idx < NGENES) {
    float s = 0.f;
    int n = 0;
    for (int c = 0; c < NCH; ++c) {
      s += pdv[(size_t)c * GSTRIDE + idx];
      n += pcnt[(size_t)c * GSTRIDE + idx];
    }
    dv_inv[idx] = 1.f / sqrtf(s + 1e-6f);
    row_cnt[idx] = n;
  } else if (idx >= BIN0 && idx < BIN0 + NBIN) {
    int b = idx - BIN0;  // tile-major bin id
    int t = b / NEDGES, e = b - t * NEDGES;
    int run = 0;
    for (int c = 0; c < NCH; ++c) {
      ccpre8[(size_t)c * NBIN + b] = run;
      run += pbc[(size_t)c * NBIN + b];
    }
    cnt8em[(e << 3) | t] = run;  // edge-major total (scan order)
  } else if (idx >= EDGE0 && idx < EDGE0 + NEDGES) {
    int e = idx - EDGE0;
    float s = 0.f;
    for (int cp = 0; cp < NCH * 4; ++cp) s += pde[(size_t)cp * NEDGES + e];
    de_inv[e] = 1.f / (s + 1e-6f);
  }
}

// ---- hierarchical coalesced scans over cnt8em (40000) and row_cnt (50000) ----
__global__ void k_sc1(const int* __restrict__ cnt8em, const int* __restrict__ row_cnt,
                      int* __restrict__ bsum) {
  __shared__ int wsum[4];
  int blk = blockIdx.x, t = threadIdx.x, lane = t & 63, wid = t >> 6;
  const int* in;
  int base, n;
  if (blk < SCB_BIN) { in = cnt8em; base = blk * 1024; n = NBIN; }
  else { in = row_cnt; base = (blk - SCB_BIN) * 1024; n = NGENES; }
  int s = 0;
#pragma unroll
  for (int k = 0; k < 4; ++k) {
    int e = base + t + k * 256;
    if (e < n) s += in[e];
  }
  s = wred_sumi(s);
  if (lane == 0) wsum[wid] = s;
  __syncthreads();
  if (t == 0) bsum[blk] = wsum[0] + wsum[1] + wsum[2] + wsum[3];
}

__global__ void k_sc2(const int* __restrict__ bsum, int* __restrict__ boff) {
  int t = threadIdx.x, lane = t & 63, wid = t >> 6;
  if (wid == 0) {
    int x = (lane < SCB_BIN) ? bsum[lane] : 0;
    int incl = wave_incl_scan(x);
    if (lane < SCB_BIN) boff[lane] = incl - x;
  } else {
    int x = (lane < SCB_ROW) ? bsum[SCB_BIN + lane] : 0;
    int incl = wave_incl_scan(x);
    if (lane < SCB_ROW) boff[SCB_BIN + lane] = incl - x;
  }
}

__global__ void k_sc3(const int* __restrict__ cnt8em, const int* __restrict__ row_cnt,
                      const int* __restrict__ boff,
                      int* __restrict__ start8, int* __restrict__ row_start) {
  __shared__ int lds[1024];
  __shared__ int wsum[4];
  int blk = blockIdx.x, t = threadIdx.x, lane = t & 63, wid = t >> 6;
  const int* in;
  int* out;
  int base, n;
  if (blk < SCB_BIN) { in = cnt8em; out = start8; base = blk * 1024; n = NBIN; }
  else { in = row_cnt; out = row_start; base = (blk - SCB_BIN) * 1024; n = NGENES; }
  int coff = boff[blk];
#pragma unroll
  for (int k = 0; k < 4; ++k) {
    int e = t + k * 256;
    lds[e] = (base + e < n) ? in[base + e] : 0;
  }
  __syncthreads();
  int x0 = lds[4 * t], x1 = lds[4 * t + 1], x2 = lds[4 * t + 2], x3 = lds[4 * t + 3];
  int s = x0 + x1 + x2 + x3;
  int incl = wave_incl_scan(s);
  if (lane == 63) wsum[wid] = incl;
  __syncthreads();
  int woff = 0;
  for (int w = 0; w < wid; ++w) woff += wsum[w];
  int tb = coff + woff + incl - s;
  int i0 = base + 4 * t;
  if (i0 + 3 < n) {
    ((int4*)(out + i0))[0] = make_int4(tb, tb + x0, tb + x0 + x1, tb + x0 + x1 + x2);
  } else {
    if (i0 < n) out[i0] = tb;
    if (i0 + 1 < n) out[i0 + 1] = tb + x0;
    if (i0 + 2 < n) out[i0 + 2] = tb + x0 + x1;
    if (i0 + 3 < n) out[i0 + 3] = tb + x0 + x1 + x2;
  }
}

// MERGED placement. grid (NCH, 5), 1024 thr.
__global__ void k_place(const int* __restrict__ rows, const int* __restrict__ cols,
                        const float* __restrict__ vals, const float* __restrict__ dv_inv,
                        const int* __restrict__ start8, const int* __restrict__ ccpre8,
                        const int* __restrict__ row_start, int* __restrict__ row_cur,
                        const unsigned* __restrict__ bitmap,
                        int2* __restrict__ csc, int2* __restrict__ csr) {
  __shared__ char smem_raw[40000];
  int c = blockIdx.x, role = blockIdx.y, tid = threadIdx.x;
  int lo = c * (NNZ_C / NCH), hi = lo + (NNZ_C / NCH);
  if (role < 4) {
    int* cnt_s = (int*)smem_raw;  // 2*NEDGES ints = 40000 B
    for (int j = tid; j < 2 * NEDGES; j += 1024) cnt_s[j] = 0;
    __syncthreads();
    const int* cp = ccpre8 + (size_t)c * NBIN;
    for (int i = lo + tid; i < hi; i += 1024) {
      int r = rows[i];
      int t = r / TILESZ;
      if ((t >> 1) != role) continue;
      int e = cols[i];
      float w = vals[i] * dv_inv[r];
      int rank = atomicAdd(&cnt_s[(t & 1) * NEDGES + e], 1);
      int pos = start8[e * 8 + t] + cp[t * NEDGES + e] + rank;
      csc[pos] = make_int2(r, __float_as_int(w));
    }
  } else {
    unsigned* bm_s = (unsigned*)smem_raw;  // 6272 B
    for (int j = tid; j < NBMW; j += 1024) bm_s[j] = bitmap[j];
    __syncthreads();
    for (int i = lo + tid; i < hi; i += 1024) {
      int r = rows[i];
      if ((bm_s[r >> 5] >> (r & 31)) & 1) {
        int p2 = row_start[r] + atomicAdd(row_cur + r, 1);
        if (p2 < CSRCAP) csr[p2] = make_int2(cols[i], __float_as_int(vals[i]));
      }
    }
  }
}

// XCD-affine tiled edge pass: block bid -> (e=bid>>3, tile t=bid&7).
__global__ void k_edge_t(const int* __restrict__ start8, const int* __restrict__ cnt8em,
                         const int2* __restrict__ csc, const float* __restrict__ ge,
                         float* __restrict__ part) {
  __shared__ float4 red[32];
  int bid = blockIdx.x;
  int s = start8[bid];
  int n = cnt8em[bid];
  int g = threadIdx.x >> 5, l = threadIdx.x & 31;
  float4 a0 = make_float4(0.f, 0.f, 0.f, 0.f);
  float4 a1 = make_float4(0.f, 0.f, 0.f, 0.f);
  float4 a2 = make_float4(0.f, 0.f, 0.f, 0.f);
  float4 a3 = make_float4(0.f, 0.f, 0.f, 0.f);
  int i = s + g;
  int end = s + n;
  for (; i + 6 < end; i += 8) {
    int2 e0 = csc[i];
    int2 e1 = csc[i + 2];
    int2 e2 = csc[i + 4];
    int2 e3 = csc[i + 6];
    float4 x0 = *((const float4*)(ge + (size_t)e0.x * DIM) + l);
    float4 x1 = *((const float4*)(ge + (size_t)e1.x * DIM) + l);
    float4 x2 = *((const float4*)(ge + (size_t)e2.x * DIM) + l);
    float4 x3 = *((const float4*)(ge + (size_t)e3.x * DIM) + l);
    float w0 = __int_as_float(e0.y), w1 = __int_as_float(e1.y);
    float w2 = __int_as_float(e2.y), w3 = __int_as_float(e3.y);
    a0.x += w0 * x0.x; a0.y += w0 * x0.y; a0.z += w0 * x0.z; a0.w += w0 * x0.w;
    a1.x += w1 * x1.x; a1.y += w1 * x1.y; a1.z += w1 * x1.z; a1.w += w1 * x1.w;
    a2.x += w2 * x2.x; a2.y += w2 * x2.y; a2.z += w2 * x2.z; a2.w += w2 * x2.w;
    a3.x += w3 * x3.x; a3.y += w3 * x3.y; a3.z += w3 * x3.z; a3.w += w3 * x3.w;
  }
  for (; i < end; i += 2) {
    int2 en = csc[i];
    float w = __int_as_float(en.y);
    float4 x = *((const float4*)(ge + (size_t)en.x * DIM) + l);
    a0.x += w * x.x; a0.y += w * x.y; a0.z += w * x.z; a0.w += w * x.w;
  }
  a0.x += a1.x + a2.x + a3.x;
  a0.y += a1.y + a2.y + a3.y;
  a0.z += a1.z + a2.z + a3.z;
  a0.w += a1.w + a2.w + a3.w;
  if (g == 1) red[l] = a0;
  __syncthreads();
  if (g == 0) {
    float4 b = red[l];
    a0.x += b.x; a0.y += b.y; a0.z += b.z; a0.w += b.w;
    *((float4*)(part + (size_t)bid * DIM) + l) = a0;
  }
}

// HXde[e,:] = de_inv[e] * sum_t part[e*8+t,:]
__global__ void k_edge_red(const float* __restrict__ part, const float* __restrict__ de_inv,
                           float* __restrict__ HXde) {
  int e = blockIdx.x, d = threadIdx.x;
  float s = 0.f;
#pragma unroll
  for (int t = 0; t < NT; ++t) s += part[((size_t)e * 8 + t) * DIM + d];
  HXde[(size_t)e * DIM + d] = s * de_inv[e];
}

// pass C fused with gene_ids gather; 4 groups, 2-deep unroll (proven form)
__global__ void k_gene(const int* __restrict__ gene_ids, const int* __restrict__ row_start,
                       const int* __restrict__ row_cnt, const int2* __restrict__ csr,
                       const float* __restrict__ HXde, const float* __restrict__ dv_inv,
                       float* __restrict__ Xg) {
  __shared__ float4 red[4][32];
  int bm = blockIdx.x;
  int gene = gene_ids[bm];
  int s = row_start[gene], n = row_cnt[gene];
  int end = s + n;
  int g = threadIdx.x >> 5, l = threadIdx.x & 31;
  float4 a0 = make_float4(0.f, 0.f, 0.f, 0.f);
  float4 a1 = make_float4(0.f, 0.f, 0.f, 0.f);
  int i = s + g;
  for (; i + 4 < end; i += 8) {
    int2 e0 = csr[i];
    int2 e1 = csr[i + 4];
    float4 x0 = *((const float4*)(HXde + (size_t)e0.x * DIM) + l);
    float4 x1 = *((const float4*)(HXde + (size_t)e1.x * DIM) + l);
    float v0 = __int_as_float(e0.y), v1 = __int_as_float(e1.y);
    a0.x += v0 * x0.x; a0.y += v0 * x0.y; a0.z += v0 * x0.z; a0.w += v0 * x0.w;
    a1.x += v1 * x1.x; a1.y += v1 * x1.y; a1.z += v1 * x1.z; a1.w += v1 * x1.w;
  }
  for (; i < end; i += 4) {
    int2 en = csr[i];
    float v = __int_as_float(en.y);
    float4 x = *((const float4*)(HXde + (size_t)en.x * DIM) + l);
    a0.x += v * x.x; a0.y += v * x.y; a0.z += v * x.z; a0.w += v * x.w;
  }
  a0.x += a1.x; a0.y += a1.y; a0.z += a1.z; a0.w += a1.w;
  red[g][l] = a0;
  __syncthreads();
  if (g == 0) {
    float4 a = red[0][l], b = red[1][l], c = red[2][l], d = red[3][l];
    float dvg = dv_inv[gene];
    float4 o;
    o.x = (a.x + b.x + c.x + d.x) * dvg;
    o.y = (a.y + b.y + c.y + d.y) * dvg;
    o.z = (a.z + b.z + c.z + d.z) * dvg;
    o.w = (a.w + b.w + c.w + d.w) * dvg;
    *((float4*)(Xg + (size_t)bm * DIM) + l) = o;
  }
}

// rep[b,p,d] = (sum_m Xg[b,m,d]*mask[m,p]) / max(cnt[p],1)
// LDS-staged, double-buffered: 128 threads cooperatively vector-load 25 mask rows
// (500 floats) per chunk with high MLP, compute previous chunk from LDS broadcast
// (ds_read_b128). Converts the SGPR-limited serial s_load chain (27% VALUBusy in
// the dense form) into parallel vector loads. Summation order identical to dense.
#define PT 20
#define CHM 25   // m's per staged chunk; MM/CHM = 8 chunks exactly
__global__ void k_pathway(const int* __restrict__ gene_ids,
                          const float* __restrict__ gene_pathway,
                          const float* __restrict__ Xg, float* __restrict__ rep) {
  __shared__ __align__(16) float buf[2][CHM * PT];  // 2 x 2000 B
  __shared__ int gid_s[MM];
  int b = blockIdx.y;
  int p0 = blockIdx.x * PT;
  int t = threadIdx.x;
  int d = t;
  if (t < 128) gid_s[t] = gene_ids[b * MM + t];
  if (t + 128 < MM) gid_s[t + 128] = gene_ids[b * MM + t + 128];
  __syncthreads();
  float acc[PT], cnt[PT];
#pragma unroll
  for (int pp = 0; pp < PT; ++pp) { acc[pp] = 0.f; cnt[pp] = 0.f; }
  // prefetch chunk 0 into registers
  float r[4];
#pragma unroll
  for (int k = 0; k < 4; ++k) {
    int e = t + k * 128;
    if (e < CHM * PT) {
      int ml = e / PT, po = e - ml * PT;
      r[k] = gene_pathway[(size_t)gid_s[ml] * NPATH + p0 + po];
    }
  }
  const float* Xb = Xg + (size_t)b * MM * DIM + d;
  for (int ch = 0; ch < MM / CHM; ++ch) {
    float* bw = buf[ch & 1];
#pragma unroll
    for (int k = 0; k < 4; ++k) {
      int e = t + k * 128;
      if (e < CHM * PT) bw[e] = r[k];
    }
    __syncthreads();
    // prefetch next chunk (independent of compute below)
    if (ch + 1 < MM / CHM) {
      int m0n = (ch + 1) * CHM;
#pragma unroll
      for (int k = 0; k < 4; ++k) {
        int e = t + k * 128;
        if (e < CHM * PT) {
          int ml = e / PT, po = e - ml * PT;
          r[k] = gene_pathway[(size_t)gid_s[m0n + ml] * NPATH + p0 + po];
        }
      }
    }
    const float* br = buf[ch & 1];
    int m0 = ch * CHM;
    for (int ml = 0; ml < CHM; ++ml) {
      float x = Xb[(size_t)(m0 + ml) * DIM];
      const float4* mr = (const float4*)(br + ml * PT);
#pragma unroll
      for (int q = 0; q < 5; ++q) {
        float4 v = mr[q];
        acc[4 * q + 0] += v.x * x; cnt[4 * q + 0] += v.x;
        acc[4 * q + 1] += v.y * x; cnt[4 * q + 1] += v.y;
        acc[4 * q + 2] += v.z * x; cnt[4 * q + 2] += v.z;
        acc[4 * q + 3] += v.w * x; cnt[4 * q + 3] += v.w;
      }
    }
    // single sync per chunk is sufficient: next iteration writes the OTHER
    // buffer, and the sync above gates any thread from being 2 chunks ahead.
  }
#pragma unroll
  for (int pp = 0; pp < PT; ++pp) {
    rep[((size_t)b * NPATH + p0 + pp) * DIM + d] = acc[pp] / fmaxf(cnt[pp], 1.f);
  }
}

// scores[b,p] = tanh(rep@W1_top + ctx@W1_bot + b1) @ W2 + b2   (ctxw inlined)
#define PT2 10
__global__ void k_attn(const float* __restrict__ rep, const int* __restrict__ context_ids,
                       const float* __restrict__ treatment_embed,
                       const float* __restrict__ W1, const float* __restrict__ b1,
                       const float* __restrict__ W2, const float* __restrict__ b2,
                       float* __restrict__ scores) {
  __shared__ float in_s[PT2][DIM];
  __shared__ float ctx_s[DIM];
  __shared__ float part[PT2][2];
  int b = blockIdx.y;
  int p0 = blockIdx.x * PT2;
  int j = threadIdx.x;
  int lane = j & 63, wid = j >> 6;
  ctx_s[j] = treatment_embed[context_ids[b] * DIM + j];
#pragma unroll
  for (int pp = 0; pp < PT2; ++pp)
    in_s[pp][j] = rep[((size_t)b * NPATH + p0 + pp) * DIM + j];
  __syncthreads();
  float base = b1[j];
  for (int k = 0; k < DIM; ++k) base += ctx_s[k] * W1[(DIM + k) * DIM + j];
  float acc[PT2];
#pragma unroll
  for (int pp = 0; pp < PT2; ++pp) acc[pp] = base;
  for (int k = 0; k < DIM; ++k) {
    float w1 = W1[k * DIM + j];
#pragma unroll
    for (int pp = 0; pp < PT2; ++pp) acc[pp] += in_s[pp][k] * w1;
  }
  float w2 = W2[j];
#pragma unroll
  for (int pp = 0; pp < PT2; ++pp) {
    float t = tanhf(acc[pp]) * w2;
    t = wred_sum(t);
    if (lane == 0) part[pp][wid] = t;
  }
  __syncthreads();
  if (j < PT2) scores[b * NPATH + p0 + j] = part[j][0] + part[j][1] + b2[0];
}

// softmax + z0 + z + risk, one block per b (128 threads)
__global__ void k_final(const float* __restrict__ scores, const float* __restrict__ rep,
                        const float* __restrict__ latent_W, const float* __restrict__ latent_b,
                        const float* __restrict__ risk_W, const float* __restrict__ risk_b,
                        float* __restrict__ out) {
  __shared__ float w_s[NPATH];
  __shared__ float z0_s[DIM];
  __shared__ float red_max[2], red_sum[2], red_risk[2];
  int b = blockIdx.x, t = threadIdx.x;
  int lane = t & 63, wid = t >> 6;
  float lmax = -3.4e38f;
  for (int p = t; p < NPATH; p += 128) {
    float s = scores[b * NPATH + p];
    w_s[p] = s;
    lmax = fmaxf(lmax, s);
  }
  lmax = wred_max(lmax);
  if (lane == 0) red_max[wid] = lmax;
  __syncthreads();
  float bmax = fmaxf(red_max[0], red_max[1]);
  float lsum = 0.f;
  for (int p = t; p < NPATH; p += 128) {
    float e = expf(w_s[p] - bmax);
    w_s[p] = e;
    lsum += e;
  }
  lsum = wred_sum(lsum);
  if (lane == 0) red_sum[wid] = lsum;
  __syncthreads();
  float inv = 1.f / (red_sum[0] + red_sum[1]);
  int d = t;
  const float* repb = rep + (size_t)b * NPATH * DIM + d;
  float z00 = 0.f, z01 = 0.f, z02 = 0.f, z03 = 0.f;
  for (int p = 0; p < NPATH; p += 4) {
    z00 += w_s[p] * repb[(size_t)p * DIM];
    z01 += w_s[p + 1] * repb[(size_t)(p + 1) * DIM];
    z02 += w_s[p + 2] * repb[(size_t)(p + 2) * DIM];
    z03 += w_s[p + 3] * repb[(size_t)(p + 3) * DIM];
  }
  float z0 = ((z00 + z01) + (z02 + z03)) * inv;
  z0_s[d] = z0;
  __syncthreads();
  float z = latent_b[t];
  for (int dd = 0; dd < DIM; ++dd) z += z0_s[dd] * latent_W[dd * DIM + t];
  out[BB + b * DIM + t] = z;
  float r = z * risk_W[t];
  r = wred_sum(r);
  if (lane == 0) red_risk[wid] = r;
  __syncthreads();
  if (t == 0) out[b] = red_risk[0] + red_risk[1] + risk_b[0];
}

extern "C" void kernel_launch(void* const* d_in, const int* in_sizes, int n_in,
                              void* d_out, int out_size, void* d_ws, size_t ws_size,
                              hipStream_t stream) {
  const int* gene_ids = (const int*)d_in[0];
  const int* context_ids = (const int*)d_in[1];
  const int* H_rows = (const int*)d_in[2];
  const int* H_cols = (const int*)d_in[3];
  const float* H_vals = (const float*)d_in[4];
  const float* gene_embed = (const float*)d_in[5];
  const float* treatment_embed = (const float*)d_in[6];
  const float* gene_pathway = (const float*)d_in[7];
  const float* W1 = (const float*)d_in[8];
  const float* b1 = (const float*)d_in[9];
  const float* W2 = (const float*)d_in[10];
  const float* b2 = (const float*)d_in[11];
  const float* latent_W = (const float*)d_in[12];
  const float* latent_b = (const float*)d_in[13];
  const float* risk_W = (const float*)d_in[14];
  const float* risk_b = (const float*)d_in[15];
  float* out = (float*)d_out;

  char* ws = (char*)d_ws;
  // --- meta ---
  float* dv_inv = (float*)(ws + 0);             // -> 200000
  float* de_inv = (float*)(ws + 200000);        // -> 220000
  int* row_cnt = (int*)(ws + 220000);           // -> 420000
  int* row_start = (int*)(ws + 420000);         // -> 620000
  int* cnt8em = (int*)(ws + 620000);            // [e][t] 40000 -> 780000
  int* start8 = (int*)(ws + 780000);            // [e][t] 40000 -> 940000
  int* ccpre8 = (int*)(ws + 940000);            // [32][40000] -> 6060000
  float* scores = (float*)(ws + 6060000);       // -> 6188000
  int* bsum = (int*)(ws + 6220800);             // 89 -> pad 6221312
  int* boff = (int*)(ws + 6221312);             // 89 -> pad 6221824
  // --- memset zone ---
  int* row_cur = (int*)(ws + 6349824);          // -> 6549824
  unsigned* bitmap = (unsigned*)(ws + 6549824); // -> 6556096
  // --- sparse structures (written after k_reduce) ---
  int2* csc = (int2*)(ws + 6556096);            // 12.8M -> 19356096
  int2* csr = (int2*)(ws + 19356096);           // 3.2M -> 22556096
  float* HXde = (float*)(ws + 22556096);        // 2.56M -> 25116096
  float* part = (float*)(ws + 25116096);        // [40000][128]f 20.48M -> 45596096
  // --- hist partials ALIAS csc/csr/HXde/part-head (dead after k_reduce) ---
  float* pdv = (float*)(ws + 6556096);          // 32*50048*4 -> 12962240
  int* pcnt = (int*)(ws + 12962240);            // 32*50048*4 -> 19368384
  int* pbc = (int*)(ws + 19368384);             // 32*40000*4 -> 24488384
  float* pde = (float*)(ws + 24488384);         // 32*4*5000*4 -> 27048384
  // --- Xg/rep ALIAS part (part dead after k_edge_red) ---
  float* Xg = (float*)(ws + 25116096);          // 6.55M -> 31669696
  float* rep = (float*)(ws + 31669696);         // 16.38M -> 48053696 (peak 48.05MB)

  hipMemsetAsync(ws + 6349824, 0, 206272, stream);  // row_cur + bitmap

  k_mark<<<(BMN + 255) / 256, 256, 0, stream>>>(gene_ids, bitmap);
  k_build<<<dim3(NCH, 12), 1024, 0, stream>>>(H_rows, H_cols, H_vals, bitmap,
                                              pdv, pcnt, pbc, pde);
  k_reduce<<<(RED_N + 255) / 256, 256, 0, stream>>>(pdv, pcnt, pbc, pde, dv_inv, row_cnt,
                                                    ccpre8, cnt8em, de_inv);
  k_sc1<<<SCB, 256, 0, stream>>>(cnt8em, row_cnt, bsum);
  k_sc2<<<1, 128, 0, stream>>>(bsum, boff);
  k_sc3<<<SCB, 256, 0, stream>>>(cnt8em, row_cnt, boff, start8, row_start);
  k_place<<<dim3(NCH, 5), 1024, 0, stream>>>(H_rows, H_cols, H_vals, dv_inv,
                                             start8, ccpre8, row_start, row_cur,
                                             bitmap, csc, csr);
  k_edge_t<<<NBIN, 64, 0, stream>>>(start8, cnt8em, csc, gene_embed, part);
  k_edge_red<<<NEDGES, DIM, 0, stream>>>(part, de_inv, HXde);
  k_gene<<<BMN, 128, 0, stream>>>(gene_ids, row_start, row_cnt, csr, HXde, dv_inv, Xg);
  k_pathway<<<dim3(NPATH / PT, BB), DIM, 0, stream>>>(gene_ids, gene_pathway, Xg, rep);
  k_attn<<<dim3(NPATH / PT2, BB), DIM, 0, stream>>>(rep, context_ids, treatment_embed,
                                                    W1, b1, W2, b2, scores);
  k_final<<<BB, DIM, 0, stream>>>(scores, rep, latent_W, latent_b, risk_W, risk_b, out);
}